// Round 6
// baseline (380.760 us; speedup 1.0000x reference)
//
#include <hip/hip_runtime.h>
#include <math.h>

// Problem constants (B=8, H=8, N=2048, C=64). fp32 inputs/outputs.
// Q staged in d_ws as bf16, PRE-SCALED by C^-0.5 * log2(e) (so flash uses
// exp2 = bare v_exp_f32). K natural [head][n][c]; V transposed Vt[head][c][n].
// Flash: no K/V LDS staging -- MFMA fragments loaded directly from global
// (L1/L2-resident), zero __syncthreads in the K-loop. Only LDS use is the
// wave-private P C-layout -> A-layout round-trip.
#define BH    64
#define NSEQ  2048
#define CDIM  64
#define KSTR  72   // LDS row stride in bf16 (144B, 16B-aligned)
#define VLS   136  // proj V-transpose tile: n stride (128 + 8 pad)

typedef unsigned short ushort_t;
typedef __attribute__((ext_vector_type(8))) short short8;    // 8 bf16 (4 VGPR)
typedef __attribute__((ext_vector_type(4))) float float4v;   // mfma C/D

// fp32 -> bf16 bits, round-to-nearest-even
__device__ __forceinline__ ushort_t f32_to_bf16_rne(float x) {
  unsigned int u = __float_as_uint(x);
  u += 0x7fffu + ((u >> 16) & 1u);
  return (ushort_t)(u >> 16);
}

// ---------------- QKV projection (MFMA) ----------------
// qkv[row, d] = sum_c x[row, c] * W[d, c];  d<64 -> Q (x 0.125*log2e), <128 -> K, else V.
// Block: 256 threads = 4 waves, 128 rows (32/wave). W staged once in LDS (bf16).
__global__ __launch_bounds__(256) void qkv_proj_mfma(
    const float* __restrict__ x, const float* __restrict__ w,
    ushort_t* __restrict__ q, ushort_t* __restrict__ k,
    ushort_t* __restrict__ vt) {
  __shared__ ushort_t Wb[192 * KSTR];   // 27648 B
  __shared__ ushort_t Vl[64 * VLS];     // 17408 B: V tile transposed [c][n_local]
  const int t = threadIdx.x;
  const int lane = t & 63, wv = t >> 6;
  const int quad = lane >> 4, l16 = lane & 15;
  const long rowbase = (long)blockIdx.x * 128;
  const int head  = (int)(rowbase >> 11);
  const int nbase = (int)(rowbase & 2047);

  // stage W as bf16; Q-rows (d<64) pre-scaled by 0.125*log2(e)
  for (int u = t; u < 1536; u += 256) {
    const int d = u >> 3, o8 = (u & 7) * 8;
    const float sc = (d < 64) ? 0.1803368801111244f : 1.0f;  // 0.125*log2(e)
    const float4 f0 = *reinterpret_cast<const float4*>(w + d * 64 + o8);
    const float4 f1 = *reinterpret_cast<const float4*>(w + d * 64 + o8 + 4);
    ushort_t tmp[8] __attribute__((aligned(16)));
    tmp[0] = f32_to_bf16_rne(f0.x * sc); tmp[1] = f32_to_bf16_rne(f0.y * sc);
    tmp[2] = f32_to_bf16_rne(f0.z * sc); tmp[3] = f32_to_bf16_rne(f0.w * sc);
    tmp[4] = f32_to_bf16_rne(f1.x * sc); tmp[5] = f32_to_bf16_rne(f1.y * sc);
    tmp[6] = f32_to_bf16_rne(f1.z * sc); tmp[7] = f32_to_bf16_rne(f1.w * sc);
    *reinterpret_cast<uint4*>(&Wb[d * KSTR + o8]) = *reinterpret_cast<const uint4*>(tmp);
  }
  __syncthreads();

  // A-frags: x rows, converted to bf16
  short8 xf[2][2];
#pragma unroll
  for (int tm = 0; tm < 2; ++tm)
#pragma unroll
    for (int kb = 0; kb < 2; ++kb) {
      const float* xp = x + (rowbase + wv * 32 + tm * 16 + l16) * 64 + kb * 32 + quad * 8;
      const float4 f0 = *reinterpret_cast<const float4*>(xp);
      const float4 f1 = *reinterpret_cast<const float4*>(xp + 4);
      ushort_t tmp[8] __attribute__((aligned(16)));
      tmp[0] = f32_to_bf16_rne(f0.x); tmp[1] = f32_to_bf16_rne(f0.y);
      tmp[2] = f32_to_bf16_rne(f0.z); tmp[3] = f32_to_bf16_rne(f0.w);
      tmp[4] = f32_to_bf16_rne(f1.x); tmp[5] = f32_to_bf16_rne(f1.y);
      tmp[6] = f32_to_bf16_rne(f1.z); tmp[7] = f32_to_bf16_rne(f1.w);
      xf[tm][kb] = *reinterpret_cast<const short8*>(tmp);
    }

  float4v acc[2][12];
#pragma unroll
  for (int tm = 0; tm < 2; ++tm)
#pragma unroll
    for (int nt = 0; nt < 12; ++nt)
#pragma unroll
      for (int r = 0; r < 4; ++r) acc[tm][nt][r] = 0.f;

#pragma unroll
  for (int kb = 0; kb < 2; ++kb)
#pragma unroll
    for (int nt = 0; nt < 12; ++nt) {
      const short8 wf = *reinterpret_cast<const short8*>(
          &Wb[(nt * 16 + l16) * KSTR + kb * 32 + quad * 8]);
      acc[0][nt] = __builtin_amdgcn_mfma_f32_16x16x32_bf16(xf[0][kb], wf, acc[0][nt], 0, 0, 0);
      acc[1][nt] = __builtin_amdgcn_mfma_f32_16x16x32_bf16(xf[1][kb], wf, acc[1][nt], 0, 0, 0);
    }

  // write out: C-layout D[row=quad*4+r][col=l16] per 16x16 tile
#pragma unroll
  for (int tm = 0; tm < 2; ++tm)
#pragma unroll
    for (int nt = 0; nt < 12; ++nt)
#pragma unroll
      for (int r = 0; r < 4; ++r) {
        const int row_local = wv * 32 + tm * 16 + quad * 4 + r;
        const ushort_t val = f32_to_bf16_rne(acc[tm][nt][r]);
        const int d = nt * 16 + l16;
        if (nt < 4)      q[(rowbase + row_local) * 64 + d] = val;
        else if (nt < 8) k[(rowbase + row_local) * 64 + (d - 64)] = val;
        else             Vl[(d - 128) * VLS + row_local] = val;   // transpose via LDS
      }
  __syncthreads();

  // coalesced Vt store: vt[head][c][nbase + n], 64 x 128 tile in 16B chunks
#pragma unroll
  for (int i = 0; i < 4; ++i) {
    const int uidx = t + i * 256;          // 1024 units
    const int c = uidx >> 4, n0 = (uidx & 15) * 8;
    *reinterpret_cast<uint4*>(vt + (long)head * (64 * 2048) + (long)c * 2048 + nbase + n0) =
        *reinterpret_cast<const uint4*>(&Vl[c * VLS + n0]);
  }
}

// ---------------- MFMA flash attention (no-max softmax, barrier-free loop) --
// block: 256 threads = 4 waves. TQ=128 (32 rows/wave), TK=64.
// mfma_f32_16x16x32_bf16 layouts (HW-verified):
//   A: lane holds A[m=lane&15][k=quad*8+j]   (contiguous 8 bf16)
//   B: lane holds B'[n=lane&15][k=quad*8+j]  (B' = source in [n][k] natural)
//   C/D: lane reg holds D[row=quad*4+reg][col=lane&15]
__global__ __launch_bounds__(256, 3) void flash_attn_mfma(
    const ushort_t* __restrict__ q, const ushort_t* __restrict__ k,
    const ushort_t* __restrict__ vt, float* __restrict__ out) {
  __shared__ ushort_t Ps[128 * KSTR];   // P [q_row][kv_row], per-wave slices (18.4 KB)
  const int t = threadIdx.x;
  const int lane = t & 63, w = t >> 6;
  const int quad = lane >> 4, l16 = lane & 15;
  const int qt = blockIdx.x, bh = blockIdx.y;
  const long hoff = (long)bh * NSEQ * CDIM;
  const ushort_t* qp  = q  + hoff + (long)qt * 128 * CDIM;
  const ushort_t* kp  = k  + hoff;
  const ushort_t* vtp = vt + hoff;     // [64][2048]

  // Q fragments (pre-scaled by 0.125*log2e at proj time), loaded once
  short8 qf[2][2];
#pragma unroll
  for (int tm = 0; tm < 2; ++tm)
#pragma unroll
    for (int kb = 0; kb < 2; ++kb)
      qf[tm][kb] = *reinterpret_cast<const short8*>(
          qp + (w * 32 + tm * 16 + l16) * 64 + kb * 32 + quad * 8);

  float4v O[2][4];
  float rs[2][4];
#pragma unroll
  for (int tm = 0; tm < 2; ++tm)
#pragma unroll
    for (int r = 0; r < 4; ++r) {
      rs[tm][r] = 0.f;
#pragma unroll
      for (int ct = 0; ct < 4; ++ct) O[tm][ct][r] = 0.f;
    }

  for (int tile = 0; tile < NSEQ / 64; ++tile) {
    // K and Vt fragments straight from global (L1/L2-resident; 16B/lane)
    short8 kf[2][4], vf[2][4];
#pragma unroll
    for (int kb = 0; kb < 2; ++kb)
#pragma unroll
      for (int nt = 0; nt < 4; ++nt)
        kf[kb][nt] = *reinterpret_cast<const short8*>(
            kp + ((long)tile * 64 + nt * 16 + l16) * 64 + kb * 32 + quad * 8);
#pragma unroll
    for (int kb = 0; kb < 2; ++kb)
#pragma unroll
      for (int ct = 0; ct < 4; ++ct)
        vf[kb][ct] = *reinterpret_cast<const short8*>(
            vtp + (long)(ct * 16 + l16) * 2048 + tile * 64 + kb * 32 + quad * 8);

    // S = Q K^T  (2x4 tiles of 16x16 per wave)
    float4v s[2][4];
#pragma unroll
    for (int tm = 0; tm < 2; ++tm)
#pragma unroll
      for (int nt = 0; nt < 4; ++nt)
#pragma unroll
        for (int r = 0; r < 4; ++r) s[tm][nt][r] = 0.f;
#pragma unroll
    for (int kb = 0; kb < 2; ++kb)
#pragma unroll
      for (int tm = 0; tm < 2; ++tm)
#pragma unroll
        for (int nt = 0; nt < 4; ++nt)
          s[tm][nt] = __builtin_amdgcn_mfma_f32_16x16x32_bf16(
              qf[tm][kb], kf[kb][nt], s[tm][nt], 0, 0, 0);

    // no-max softmax: p = exp2(s') (s' pre-scaled); private partial row sums
#pragma unroll
    for (int tm = 0; tm < 2; ++tm)
#pragma unroll
      for (int nt = 0; nt < 4; ++nt)
#pragma unroll
        for (int r = 0; r < 4; ++r) {
          const float p = __builtin_amdgcn_exp2f(s[tm][nt][r]);  // v_exp_f32
          rs[tm][r] += p;
          Ps[(w * 32 + tm * 16 + quad * 4 + r) * KSTR + nt * 16 + l16] =
              (ushort_t)((__float_as_uint(p) + 0x8000u) >> 16);  // round-half-up
        }

    // O += P @ V  (P via wave-private LDS slice: no barrier needed, lgkmcnt
    // ordering within the wave is sufficient)
#pragma unroll
    for (int kb = 0; kb < 2; ++kb) {
      short8 pf[2];
#pragma unroll
      for (int tm = 0; tm < 2; ++tm)
        pf[tm] = *reinterpret_cast<const short8*>(
            &Ps[(w * 32 + tm * 16 + l16) * KSTR + kb * 32 + quad * 8]);
#pragma unroll
      for (int tm = 0; tm < 2; ++tm)
#pragma unroll
        for (int ct = 0; ct < 4; ++ct)
          O[tm][ct] = __builtin_amdgcn_mfma_f32_16x16x32_bf16(
              pf[tm], vf[kb][ct], O[tm][ct], 0, 0, 0);
    }
  }

  // epilogue: reduce row sums across the 16 lanes of each quad, normalize,
  // head-mixing shuffle: final[b, h2, n, h*8+c2] = out_head[b, h, n, h2*8+c2]
  const int bi = bh >> 3, h = bh & 7;
#pragma unroll
  for (int tm = 0; tm < 2; ++tm)
#pragma unroll
    for (int r = 0; r < 4; ++r) {
      float l = rs[tm][r];
#pragma unroll
      for (int off = 1; off < 16; off <<= 1) l += __shfl_xor(l, off, 64);
      const float inv = 1.f / l;
      const int n = qt * 128 + w * 32 + tm * 16 + quad * 4 + r;
#pragma unroll
      for (int ct = 0; ct < 4; ++ct) {
        const int c = ct * 16 + l16;
        const int h2 = c >> 3, c2 = c & 7;
        out[(((long)(bi * 8 + h2)) * NSEQ + n) * 64 + h * 8 + c2] = O[tm][ct][r] * inv;
      }
    }
}

extern "C" void kernel_launch(void* const* d_in, const int* in_sizes, int n_in,
                              void* d_out, int out_size, void* d_ws, size_t ws_size,
                              hipStream_t stream) {
  (void)in_sizes; (void)n_in; (void)out_size; (void)ws_size;
  const float* x = (const float*)d_in[0];   // [8,8,2048,64] fp32
  const float* w = (const float*)d_in[1];   // [192,64] fp32
  float* out = (float*)d_out;               // [8,8,2048,64] fp32

  // workspace: Q(scaled),K natural + Vt transposed, bf16 bits, 16.78 MB each
  ushort_t* qws  = (ushort_t*)d_ws;
  ushort_t* kws  = qws + (size_t)BH * NSEQ * CDIM;
  ushort_t* vtws = kws + (size_t)BH * NSEQ * CDIM;

  qkv_proj_mfma<<<(BH * NSEQ) / 128, 256, 0, stream>>>(x, w, qws, kws, vtws);
  flash_attn_mfma<<<dim3(NSEQ / 128, BH), 256, 0, stream>>>(qws, kws, vtws, out);
}

// Round 7
// 210.437 us; speedup vs baseline: 1.8094x; 1.8094x over previous
//
#include <hip/hip_runtime.h>
#include <math.h>

// Problem constants (B=8, H=8, N=2048, C=64). fp32 inputs/outputs.
// Q staged in d_ws as bf16 PRE-SCALED by C^-0.5 * log2(e) (flash uses exp2 =
// bare v_exp_f32). K natural [head][n][c]; V transposed Vt[head][c][n].
// Flash: double-buffered K/V staging via __builtin_amdgcn_global_load_lds
// (width 16), XOR-swizzled LDS layout (stride 64 u16, chunk ^= row&7),
// ONE __syncthreads per K-tile. P round-trip stays wave-private (stride 72).
#define BH    64
#define NSEQ  2048
#define CDIM  64
#define KSTR  72   // Ps LDS row stride in bf16 (144B)
#define VLS   136  // proj V-transpose tile: n stride (128 + 8 pad)

typedef unsigned short ushort_t;
typedef __attribute__((ext_vector_type(8))) short short8;    // 8 bf16 (4 VGPR)
typedef __attribute__((ext_vector_type(4))) float float4v;   // mfma C/D

// fp32 -> bf16 bits, round-to-nearest-even
__device__ __forceinline__ ushort_t f32_to_bf16_rne(float x) {
  unsigned int u = __float_as_uint(x);
  u += 0x7fffu + ((u >> 16) & 1u);
  return (ushort_t)(u >> 16);
}

// async global->LDS, 16B per lane; LDS dest = wave-uniform base + lane*16
__device__ __forceinline__ void glds16(const ushort_t* g, ushort_t* l) {
  __builtin_amdgcn_global_load_lds(
      (const __attribute__((address_space(1))) void*)g,
      (__attribute__((address_space(3))) void*)l, 16, 0, 0);
}

// ---------------- QKV projection (MFMA) ----------------
// qkv[row, d] = sum_c x[row, c] * W[d, c];  d<64 -> Q (x 0.125*log2e), <128 -> K, else V.
__global__ __launch_bounds__(256) void qkv_proj_mfma(
    const float* __restrict__ x, const float* __restrict__ w,
    ushort_t* __restrict__ q, ushort_t* __restrict__ k,
    ushort_t* __restrict__ vt) {
  __shared__ ushort_t Wb[192 * KSTR];   // 27648 B
  __shared__ ushort_t Vl[64 * VLS];     // 17408 B: V tile transposed [c][n_local]
  const int t = threadIdx.x;
  const int lane = t & 63, wv = t >> 6;
  const int quad = lane >> 4, l16 = lane & 15;
  const long rowbase = (long)blockIdx.x * 128;
  const int head  = (int)(rowbase >> 11);
  const int nbase = (int)(rowbase & 2047);

  // stage W as bf16; Q-rows (d<64) pre-scaled by 0.125*log2(e)
  for (int u = t; u < 1536; u += 256) {
    const int d = u >> 3, o8 = (u & 7) * 8;
    const float sc = (d < 64) ? 0.1803368801111244f : 1.0f;  // 0.125*log2(e)
    const float4 f0 = *reinterpret_cast<const float4*>(w + d * 64 + o8);
    const float4 f1 = *reinterpret_cast<const float4*>(w + d * 64 + o8 + 4);
    ushort_t tmp[8] __attribute__((aligned(16)));
    tmp[0] = f32_to_bf16_rne(f0.x * sc); tmp[1] = f32_to_bf16_rne(f0.y * sc);
    tmp[2] = f32_to_bf16_rne(f0.z * sc); tmp[3] = f32_to_bf16_rne(f0.w * sc);
    tmp[4] = f32_to_bf16_rne(f1.x * sc); tmp[5] = f32_to_bf16_rne(f1.y * sc);
    tmp[6] = f32_to_bf16_rne(f1.z * sc); tmp[7] = f32_to_bf16_rne(f1.w * sc);
    *reinterpret_cast<uint4*>(&Wb[d * KSTR + o8]) = *reinterpret_cast<const uint4*>(tmp);
  }
  __syncthreads();

  // A-frags: x rows, converted to bf16
  short8 xf[2][2];
#pragma unroll
  for (int tm = 0; tm < 2; ++tm)
#pragma unroll
    for (int kb = 0; kb < 2; ++kb) {
      const float* xp = x + (rowbase + wv * 32 + tm * 16 + l16) * 64 + kb * 32 + quad * 8;
      const float4 f0 = *reinterpret_cast<const float4*>(xp);
      const float4 f1 = *reinterpret_cast<const float4*>(xp + 4);
      ushort_t tmp[8] __attribute__((aligned(16)));
      tmp[0] = f32_to_bf16_rne(f0.x); tmp[1] = f32_to_bf16_rne(f0.y);
      tmp[2] = f32_to_bf16_rne(f0.z); tmp[3] = f32_to_bf16_rne(f0.w);
      tmp[4] = f32_to_bf16_rne(f1.x); tmp[5] = f32_to_bf16_rne(f1.y);
      tmp[6] = f32_to_bf16_rne(f1.z); tmp[7] = f32_to_bf16_rne(f1.w);
      xf[tm][kb] = *reinterpret_cast<const short8*>(tmp);
    }

  float4v acc[2][12];
#pragma unroll
  for (int tm = 0; tm < 2; ++tm)
#pragma unroll
    for (int nt = 0; nt < 12; ++nt)
#pragma unroll
      for (int r = 0; r < 4; ++r) acc[tm][nt][r] = 0.f;

#pragma unroll
  for (int kb = 0; kb < 2; ++kb)
#pragma unroll
    for (int nt = 0; nt < 12; ++nt) {
      const short8 wf = *reinterpret_cast<const short8*>(
          &Wb[(nt * 16 + l16) * KSTR + kb * 32 + quad * 8]);
      acc[0][nt] = __builtin_amdgcn_mfma_f32_16x16x32_bf16(xf[0][kb], wf, acc[0][nt], 0, 0, 0);
      acc[1][nt] = __builtin_amdgcn_mfma_f32_16x16x32_bf16(xf[1][kb], wf, acc[1][nt], 0, 0, 0);
    }

  // write out: C-layout D[row=quad*4+r][col=l16] per 16x16 tile
#pragma unroll
  for (int tm = 0; tm < 2; ++tm)
#pragma unroll
    for (int nt = 0; nt < 12; ++nt)
#pragma unroll
      for (int r = 0; r < 4; ++r) {
        const int row_local = wv * 32 + tm * 16 + quad * 4 + r;
        const ushort_t val = f32_to_bf16_rne(acc[tm][nt][r]);
        const int d = nt * 16 + l16;
        if (nt < 4)      q[(rowbase + row_local) * 64 + d] = val;
        else if (nt < 8) k[(rowbase + row_local) * 64 + (d - 64)] = val;
        else             Vl[(d - 128) * VLS + row_local] = val;   // transpose via LDS
      }
  __syncthreads();

  // coalesced Vt store: vt[head][c][nbase + n], 64 x 128 tile in 16B chunks
#pragma unroll
  for (int i = 0; i < 4; ++i) {
    const int uidx = t + i * 256;          // 1024 units
    const int c = uidx >> 4, n0 = (uidx & 15) * 8;
    *reinterpret_cast<uint4*>(vt + (long)head * (64 * 2048) + (long)c * 2048 + nbase + n0) =
        *reinterpret_cast<const uint4*>(&Vl[c * VLS + n0]);
  }
}

// ---------------- MFMA flash attention ----------------
// block: 256 threads = 4 waves. TQ=128 (32 rows/wave), TK=64.
// K/V tiles: double-buffered LDS, swizzled layout (u16 units):
//   element [row][chunk c (8 u16)] at row*64 + (c ^ (row&7))*8
// staged by global_load_lds: wave w, call j covers rows w*16+j*8+(lane>>3),
// source chunk (lane&7)^(lane>>3), LDS dest base + lane*16B (contiguous).
// mfma_f32_16x16x32_bf16 layouts (HW-verified):
//   A: lane holds A[m=lane&15][k=quad*8+j];  B: B'[n=lane&15][k=quad*8+j]
//   C/D: lane reg holds D[row=quad*4+reg][col=lane&15]
__global__ __launch_bounds__(256, 3) void flash_attn_mfma(
    const ushort_t* __restrict__ q, const ushort_t* __restrict__ k,
    const ushort_t* __restrict__ vt, float* __restrict__ out) {
  __shared__ ushort_t Ks2[2][64 * 64];  // 16 KB
  __shared__ ushort_t Vs2[2][64 * 64];  // 16 KB
  __shared__ ushort_t Ps[128 * KSTR];   // 18 KB, P [q_row][kv], per-wave slices
  const int t = threadIdx.x;
  const int lane = t & 63, w = t >> 6;
  const int quad = lane >> 4, l16 = lane & 15;
  const int qt = blockIdx.x, bh = blockIdx.y;
  const long hoff = (long)bh * NSEQ * CDIM;
  const ushort_t* qp  = q  + hoff + (long)qt * 128 * CDIM;
  const ushort_t* kp  = k  + hoff;
  const ushort_t* vtp = vt + hoff;     // [64][2048]

  // Q fragments (pre-scaled by 0.125*log2e at proj time), loaded once
  short8 qf[2][2];
#pragma unroll
  for (int tm = 0; tm < 2; ++tm)
#pragma unroll
    for (int kb = 0; kb < 2; ++kb)
      qf[tm][kb] = *reinterpret_cast<const short8*>(
          qp + (w * 32 + tm * 16 + l16) * 64 + kb * 32 + quad * 8);

  float4v O[2][4];
  float rs[2][4];
#pragma unroll
  for (int tm = 0; tm < 2; ++tm)
#pragma unroll
    for (int r = 0; r < 4; ++r) {
      rs[tm][r] = 0.f;
#pragma unroll
      for (int ct = 0; ct < 4; ++ct) O[tm][ct][r] = 0.f;
    }

  // staging indices (per lane, constant across tiles)
  const int srow = w * 16 + (lane >> 3);         // + j*8
  const int schk = (lane & 7) ^ (lane >> 3);     // swizzled source chunk
  const int sdst = w * 16 * 64;                  // + j*8*64, u16 units

  // prologue: stage tile 0 into buffer 0
#pragma unroll
  for (int j = 0; j < 2; ++j) {
    glds16(kp + (long)(srow + j * 8) * 64 + schk * 8, &Ks2[0][sdst + j * 512]);
    glds16(vtp + (long)(srow + j * 8) * 2048 + schk * 8, &Vs2[0][sdst + j * 512]);
  }

  for (int tile = 0; tile < NSEQ / 64; ++tile) {
    const int cur = tile & 1;
    __syncthreads();   // implicit vmcnt(0): buf[cur] ready; buf[1-cur] readers done
    if (tile < NSEQ / 64 - 1) {
      const long nxt = tile + 1;
#pragma unroll
      for (int j = 0; j < 2; ++j) {
        glds16(kp + (nxt * 64 + srow + j * 8) * 64 + schk * 8,
               &Ks2[1 - cur][sdst + j * 512]);
        glds16(vtp + (long)(srow + j * 8) * 2048 + nxt * 64 + schk * 8,
               &Vs2[1 - cur][sdst + j * 512]);
      }
    }

    // S = Q K^T  (2x4 tiles of 16x16 per wave)
    float4v s[2][4];
#pragma unroll
    for (int tm = 0; tm < 2; ++tm)
#pragma unroll
      for (int nt = 0; nt < 4; ++nt)
#pragma unroll
        for (int r = 0; r < 4; ++r) s[tm][nt][r] = 0.f;

#pragma unroll
    for (int kb = 0; kb < 2; ++kb) {
      short8 kf[4];
#pragma unroll
      for (int nt = 0; nt < 4; ++nt)
        kf[nt] = *reinterpret_cast<const short8*>(
            &Ks2[cur][(nt * 16 + l16) * 64 + (((kb * 4 + quad) ^ (l16 & 7)) * 8)]);
#pragma unroll
      for (int tm = 0; tm < 2; ++tm)
#pragma unroll
        for (int nt = 0; nt < 4; ++nt)
          s[tm][nt] = __builtin_amdgcn_mfma_f32_16x16x32_bf16(
              qf[tm][kb], kf[nt], s[tm][nt], 0, 0, 0);
    }

    // no-max softmax: p = exp2(s') (pre-scaled); private partial row sums
#pragma unroll
    for (int tm = 0; tm < 2; ++tm)
#pragma unroll
      for (int nt = 0; nt < 4; ++nt)
#pragma unroll
        for (int r = 0; r < 4; ++r) {
          const float p = __builtin_amdgcn_exp2f(s[tm][nt][r]);  // v_exp_f32
          rs[tm][r] += p;
          Ps[(w * 32 + tm * 16 + quad * 4 + r) * KSTR + nt * 16 + l16] =
              (ushort_t)((__float_as_uint(p) + 0x8000u) >> 16);  // round-half-up
        }

    // O += P @ V  (P via wave-private LDS slice: lgkmcnt ordering suffices)
#pragma unroll
    for (int kb = 0; kb < 2; ++kb) {
      short8 pf[2], vf[4];
#pragma unroll
      for (int tm = 0; tm < 2; ++tm)
        pf[tm] = *reinterpret_cast<const short8*>(
            &Ps[(w * 32 + tm * 16 + l16) * KSTR + kb * 32 + quad * 8]);
#pragma unroll
      for (int ct = 0; ct < 4; ++ct)
        vf[ct] = *reinterpret_cast<const short8*>(
            &Vs2[cur][(ct * 16 + l16) * 64 + (((kb * 4 + quad) ^ (l16 & 7)) * 8)]);
#pragma unroll
      for (int tm = 0; tm < 2; ++tm)
#pragma unroll
        for (int ct = 0; ct < 4; ++ct)
          O[tm][ct] = __builtin_amdgcn_mfma_f32_16x16x32_bf16(
              pf[tm], vf[ct], O[tm][ct], 0, 0, 0);
    }
  }

  // epilogue: reduce row sums across the 16 lanes of each quad, normalize,
  // head-mixing shuffle: final[b, h2, n, h*8+c2] = out_head[b, h, n, h2*8+c2]
  const int bi = bh >> 3, h = bh & 7;
#pragma unroll
  for (int tm = 0; tm < 2; ++tm)
#pragma unroll
    for (int r = 0; r < 4; ++r) {
      float l = rs[tm][r];
#pragma unroll
      for (int off = 1; off < 16; off <<= 1) l += __shfl_xor(l, off, 64);
      const float inv = 1.f / l;
      const int n = qt * 128 + w * 32 + tm * 16 + quad * 4 + r;
#pragma unroll
      for (int ct = 0; ct < 4; ++ct) {
        const int c = ct * 16 + l16;
        const int h2 = c >> 3, c2 = c & 7;
        out[(((long)(bi * 8 + h2)) * NSEQ + n) * 64 + h * 8 + c2] = O[tm][ct][r] * inv;
      }
    }
}

extern "C" void kernel_launch(void* const* d_in, const int* in_sizes, int n_in,
                              void* d_out, int out_size, void* d_ws, size_t ws_size,
                              hipStream_t stream) {
  (void)in_sizes; (void)n_in; (void)out_size; (void)ws_size;
  const float* x = (const float*)d_in[0];   // [8,8,2048,64] fp32
  const float* w = (const float*)d_in[1];   // [192,64] fp32
  float* out = (float*)d_out;               // [8,8,2048,64] fp32

  // workspace: Q(scaled),K natural + Vt transposed, bf16 bits, 16.78 MB each
  ushort_t* qws  = (ushort_t*)d_ws;
  ushort_t* kws  = qws + (size_t)BH * NSEQ * CDIM;
  ushort_t* vtws = kws + (size_t)BH * NSEQ * CDIM;

  qkv_proj_mfma<<<(BH * NSEQ) / 128, 256, 0, stream>>>(x, w, qws, kws, vtws);
  flash_attn_mfma<<<dim3(NSEQ / 128, BH), 256, 0, stream>>>(qws, kws, vtws, out);
}

// Round 8
// 202.036 us; speedup vs baseline: 1.8846x; 1.0416x over previous
//
#include <hip/hip_runtime.h>
#include <math.h>

// Problem constants (B=8, H=8, N=2048, C=64). fp32 inputs/outputs.
// Q staged in d_ws as bf16 PRE-SCALED by C^-0.5 * log2(e) (flash uses exp2 =
// bare v_exp_f32). K natural [head][n][c]; V transposed Vt[head][c][n].
// Flash round 8: transposed dataflow. S^T = K*Q^T and O^T = Vt*P^T (mfma
// operand swap -- fragment reads unchanged). P exits with 4 contiguous kv
// per lane -> 8 ds_write_b64 (was 32 ds_write_u16); epilogue -> float4
// stores. XCD-aware grid swizzle: all 16 q-tiles of a head share id%8.
#define BH    64
#define NSEQ  2048
#define CDIM  64
#define KSTR  72   // Ps LDS row stride in bf16 (144B)
#define VLS   136  // proj V-transpose tile: n stride (128 + 8 pad)

typedef unsigned short ushort_t;
typedef __attribute__((ext_vector_type(8))) short short8;    // 8 bf16 (4 VGPR)
typedef __attribute__((ext_vector_type(4))) float float4v;   // mfma C/D

// fp32 -> bf16 bits, round-to-nearest-even
__device__ __forceinline__ ushort_t f32_to_bf16_rne(float x) {
  unsigned int u = __float_as_uint(x);
  u += 0x7fffu + ((u >> 16) & 1u);
  return (ushort_t)(u >> 16);
}

// async global->LDS, 16B per lane; LDS dest = wave-uniform base + lane*16
__device__ __forceinline__ void glds16(const ushort_t* g, ushort_t* l) {
  __builtin_amdgcn_global_load_lds(
      (const __attribute__((address_space(1))) void*)g,
      (__attribute__((address_space(3))) void*)l, 16, 0, 0);
}

// ---------------- QKV projection (MFMA) ----------------
// qkv[row, d] = sum_c x[row, c] * W[d, c];  d<64 -> Q (x 0.125*log2e), <128 -> K, else V.
__global__ __launch_bounds__(256) void qkv_proj_mfma(
    const float* __restrict__ x, const float* __restrict__ w,
    ushort_t* __restrict__ q, ushort_t* __restrict__ k,
    ushort_t* __restrict__ vt) {
  __shared__ ushort_t Wb[192 * KSTR];   // 27648 B
  __shared__ ushort_t Vl[64 * VLS];     // 17408 B: V tile transposed [c][n_local]
  const int t = threadIdx.x;
  const int lane = t & 63, wv = t >> 6;
  const int quad = lane >> 4, l16 = lane & 15;
  const long rowbase = (long)blockIdx.x * 128;
  const int head  = (int)(rowbase >> 11);
  const int nbase = (int)(rowbase & 2047);

  // stage W as bf16; Q-rows (d<64) pre-scaled by 0.125*log2(e)
  for (int u = t; u < 1536; u += 256) {
    const int d = u >> 3, o8 = (u & 7) * 8;
    const float sc = (d < 64) ? 0.1803368801111244f : 1.0f;  // 0.125*log2(e)
    const float4 f0 = *reinterpret_cast<const float4*>(w + d * 64 + o8);
    const float4 f1 = *reinterpret_cast<const float4*>(w + d * 64 + o8 + 4);
    ushort_t tmp[8] __attribute__((aligned(16)));
    tmp[0] = f32_to_bf16_rne(f0.x * sc); tmp[1] = f32_to_bf16_rne(f0.y * sc);
    tmp[2] = f32_to_bf16_rne(f0.z * sc); tmp[3] = f32_to_bf16_rne(f0.w * sc);
    tmp[4] = f32_to_bf16_rne(f1.x * sc); tmp[5] = f32_to_bf16_rne(f1.y * sc);
    tmp[6] = f32_to_bf16_rne(f1.z * sc); tmp[7] = f32_to_bf16_rne(f1.w * sc);
    *reinterpret_cast<uint4*>(&Wb[d * KSTR + o8]) = *reinterpret_cast<const uint4*>(tmp);
  }
  __syncthreads();

  // A-frags: x rows, converted to bf16
  short8 xf[2][2];
#pragma unroll
  for (int tm = 0; tm < 2; ++tm)
#pragma unroll
    for (int kb = 0; kb < 2; ++kb) {
      const float* xp = x + (rowbase + wv * 32 + tm * 16 + l16) * 64 + kb * 32 + quad * 8;
      const float4 f0 = *reinterpret_cast<const float4*>(xp);
      const float4 f1 = *reinterpret_cast<const float4*>(xp + 4);
      ushort_t tmp[8] __attribute__((aligned(16)));
      tmp[0] = f32_to_bf16_rne(f0.x); tmp[1] = f32_to_bf16_rne(f0.y);
      tmp[2] = f32_to_bf16_rne(f0.z); tmp[3] = f32_to_bf16_rne(f0.w);
      tmp[4] = f32_to_bf16_rne(f1.x); tmp[5] = f32_to_bf16_rne(f1.y);
      tmp[6] = f32_to_bf16_rne(f1.z); tmp[7] = f32_to_bf16_rne(f1.w);
      xf[tm][kb] = *reinterpret_cast<const short8*>(tmp);
    }

  float4v acc[2][12];
#pragma unroll
  for (int tm = 0; tm < 2; ++tm)
#pragma unroll
    for (int nt = 0; nt < 12; ++nt)
#pragma unroll
      for (int r = 0; r < 4; ++r) acc[tm][nt][r] = 0.f;

#pragma unroll
  for (int kb = 0; kb < 2; ++kb)
#pragma unroll
    for (int nt = 0; nt < 12; ++nt) {
      const short8 wf = *reinterpret_cast<const short8*>(
          &Wb[(nt * 16 + l16) * KSTR + kb * 32 + quad * 8]);
      acc[0][nt] = __builtin_amdgcn_mfma_f32_16x16x32_bf16(xf[0][kb], wf, acc[0][nt], 0, 0, 0);
      acc[1][nt] = __builtin_amdgcn_mfma_f32_16x16x32_bf16(xf[1][kb], wf, acc[1][nt], 0, 0, 0);
    }

  // write out: C-layout D[row=quad*4+r][col=l16] per 16x16 tile
#pragma unroll
  for (int tm = 0; tm < 2; ++tm)
#pragma unroll
    for (int nt = 0; nt < 12; ++nt)
#pragma unroll
      for (int r = 0; r < 4; ++r) {
        const int row_local = wv * 32 + tm * 16 + quad * 4 + r;
        const ushort_t val = f32_to_bf16_rne(acc[tm][nt][r]);
        const int d = nt * 16 + l16;
        if (nt < 4)      q[(rowbase + row_local) * 64 + d] = val;
        else if (nt < 8) k[(rowbase + row_local) * 64 + (d - 64)] = val;
        else             Vl[(d - 128) * VLS + row_local] = val;   // transpose via LDS
      }
  __syncthreads();

  // coalesced Vt store: vt[head][c][nbase + n], 64 x 128 tile in 16B chunks
#pragma unroll
  for (int i = 0; i < 4; ++i) {
    const int uidx = t + i * 256;          // 1024 units
    const int c = uidx >> 4, n0 = (uidx & 15) * 8;
    *reinterpret_cast<uint4*>(vt + (long)head * (64 * 2048) + (long)c * 2048 + nbase + n0) =
        *reinterpret_cast<const uint4*>(&Vl[c * VLS + n0]);
  }
}

// ---------------- MFMA flash attention (transposed dataflow) ----------------
// block: 256 threads = 4 waves. TQ=128 (32 rows/wave), TK=64. 1D grid 1024,
// XCD swizzle: bh = (id&7)*8 + (id>>3)&7, qt = id>>6.
// K/V tiles: double-buffered LDS, XOR-swizzled (stride 64 u16, chunk ^= row&7),
// staged by global_load_lds width 16; ONE __syncthreads per K-tile.
// mfma_f32_16x16x32_bf16 layouts (HW-verified): A and B share the lane map
//   op[idx=lane&15][k=quad*8+j]; C/D: reg r holds D[row=quad*4+r][col=lane&15].
// S^T = mfma(kf, qf): lane reg r = S[qrow=tm*16+l16][kv=nt*16+quad*4+r]
//   -> 4 contiguous kv per lane -> pack -> ds_write_b64 into Ps[qrow][kv].
// O^T = mfma(vf, pf): lane reg r = O[qrow=tm*16+l16][c=ct*16+quad*4+r]
//   -> float4 epilogue stores.
__global__ __launch_bounds__(256, 3) void flash_attn_mfma(
    const ushort_t* __restrict__ q, const ushort_t* __restrict__ k,
    const ushort_t* __restrict__ vt, float* __restrict__ out) {
  __shared__ ushort_t Ks2[2][64 * 64];  // 16 KB
  __shared__ ushort_t Vs2[2][64 * 64];  // 16 KB
  __shared__ ushort_t Ps[128 * KSTR];   // 18 KB, P [qrow][kv], per-wave slices
  const int t = threadIdx.x;
  const int lane = t & 63, w = t >> 6;
  const int quad = lane >> 4, l16 = lane & 15;
  const int id = blockIdx.x;
  const int qt = id >> 6;
  const int bh = ((id & 7) << 3) | ((id >> 3) & 7);   // XCD-clustered heads
  const long hoff = (long)bh * NSEQ * CDIM;
  const ushort_t* qp  = q  + hoff + (long)qt * 128 * CDIM;
  const ushort_t* kp  = k  + hoff;
  const ushort_t* vtp = vt + hoff;     // [64][2048]

  // Q fragments (pre-scaled by 0.125*log2e at proj time), loaded once.
  // Used as the B operand of S^T: lane holds Q[qrow=tm*16+l16][k=kb*32+quad*8+j].
  short8 qf[2][2];
#pragma unroll
  for (int tm = 0; tm < 2; ++tm)
#pragma unroll
    for (int kb = 0; kb < 2; ++kb)
      qf[tm][kb] = *reinterpret_cast<const short8*>(
          qp + (w * 32 + tm * 16 + l16) * 64 + kb * 32 + quad * 8);

  float4v O[4][2];   // [c-tile][q-tile], O^T C-layout
  float rs[2];
#pragma unroll
  for (int tm = 0; tm < 2; ++tm) rs[tm] = 0.f;
#pragma unroll
  for (int ct = 0; ct < 4; ++ct)
#pragma unroll
    for (int tm = 0; tm < 2; ++tm)
#pragma unroll
      for (int r = 0; r < 4; ++r) O[ct][tm][r] = 0.f;

  // staging indices (per lane, constant across tiles)
  const int srow = w * 16 + (lane >> 3);         // + j*8
  const int schk = (lane & 7) ^ (lane >> 3);     // swizzled source chunk
  const int sdst = w * 16 * 64;                  // + j*8*64, u16 units

  // prologue: stage tile 0 into buffer 0
#pragma unroll
  for (int j = 0; j < 2; ++j) {
    glds16(kp + (long)(srow + j * 8) * 64 + schk * 8, &Ks2[0][sdst + j * 512]);
    glds16(vtp + (long)(srow + j * 8) * 2048 + schk * 8, &Vs2[0][sdst + j * 512]);
  }

  for (int tile = 0; tile < NSEQ / 64; ++tile) {
    const int cur = tile & 1;
    __syncthreads();   // implicit vmcnt(0): buf[cur] ready; buf[1-cur] readers done
    if (tile < NSEQ / 64 - 1) {
      const long nxt = tile + 1;
#pragma unroll
      for (int j = 0; j < 2; ++j) {
        glds16(kp + (nxt * 64 + srow + j * 8) * 64 + schk * 8,
               &Ks2[1 - cur][sdst + j * 512]);
        glds16(vtp + (long)(srow + j * 8) * 2048 + nxt * 64 + schk * 8,
               &Vs2[1 - cur][sdst + j * 512]);
      }
    }

    // S^T = K Q^T  (4 kv-tiles x 2 q-tiles of 16x16 per wave)
    float4v s[4][2];
#pragma unroll
    for (int nt = 0; nt < 4; ++nt)
#pragma unroll
      for (int tm = 0; tm < 2; ++tm)
#pragma unroll
        for (int r = 0; r < 4; ++r) s[nt][tm][r] = 0.f;

#pragma unroll
    for (int kb = 0; kb < 2; ++kb) {
      short8 kf[4];   // A operand: lane holds K[kv=nt*16+l16][k=kb*32+quad*8+j]
#pragma unroll
      for (int nt = 0; nt < 4; ++nt)
        kf[nt] = *reinterpret_cast<const short8*>(
            &Ks2[cur][(nt * 16 + l16) * 64 + (((kb * 4 + quad) ^ (l16 & 7)) * 8)]);
#pragma unroll
      for (int nt = 0; nt < 4; ++nt)
#pragma unroll
        for (int tm = 0; tm < 2; ++tm)
          s[nt][tm] = __builtin_amdgcn_mfma_f32_16x16x32_bf16(
              kf[nt], qf[tm][kb], s[nt][tm], 0, 0, 0);
    }

    // no-max softmax: p = exp2(s') (pre-scaled); lane-private partial sums;
    // pack 4 contiguous kv -> one ds_write_b64 into Ps[qrow][kv]
#pragma unroll
    for (int tm = 0; tm < 2; ++tm)
#pragma unroll
      for (int nt = 0; nt < 4; ++nt) {
        float p0 = __builtin_amdgcn_exp2f(s[nt][tm][0]);
        float p1 = __builtin_amdgcn_exp2f(s[nt][tm][1]);
        float p2 = __builtin_amdgcn_exp2f(s[nt][tm][2]);
        float p3 = __builtin_amdgcn_exp2f(s[nt][tm][3]);
        rs[tm] += (p0 + p1) + (p2 + p3);
        uint2 pk;   // round-half-up bf16 packs
        pk.x = ((__float_as_uint(p0) + 0x8000u) >> 16) |
               ((__float_as_uint(p1) + 0x8000u) & 0xffff0000u);
        pk.y = ((__float_as_uint(p2) + 0x8000u) >> 16) |
               ((__float_as_uint(p3) + 0x8000u) & 0xffff0000u);
        *reinterpret_cast<uint2*>(
            &Ps[(w * 32 + tm * 16 + l16) * KSTR + nt * 16 + quad * 4]) = pk;
      }

    // O^T += Vt P^T  (A = Vs rows, B = P rows from Ps; wave-private slice,
    // in-order DS ops within a wave -> no barrier)
#pragma unroll
    for (int kb = 0; kb < 2; ++kb) {
      short8 pf[2], vf[4];
#pragma unroll
      for (int tm = 0; tm < 2; ++tm)
        pf[tm] = *reinterpret_cast<const short8*>(
            &Ps[(w * 32 + tm * 16 + l16) * KSTR + kb * 32 + quad * 8]);
#pragma unroll
      for (int ct = 0; ct < 4; ++ct)
        vf[ct] = *reinterpret_cast<const short8*>(
            &Vs2[cur][(ct * 16 + l16) * 64 + (((kb * 4 + quad) ^ (l16 & 7)) * 8)]);
#pragma unroll
      for (int ct = 0; ct < 4; ++ct)
#pragma unroll
        for (int tm = 0; tm < 2; ++tm)
          O[ct][tm] = __builtin_amdgcn_mfma_f32_16x16x32_bf16(
              vf[ct], pf[tm], O[ct][tm], 0, 0, 0);
    }
  }

  // epilogue: reduce row sums across quads (kv was quad-split), normalize,
  // head-mixing shuffle with float4 stores:
  // final[b, h2, n, h*8+c2] = out_head[b, h, n, h2*8+c2]
  const int bi = bh >> 3, h = bh & 7;
  float inv[2];
#pragma unroll
  for (int tm = 0; tm < 2; ++tm) {
    float l = rs[tm];
    l += __shfl_xor(l, 16, 64);
    l += __shfl_xor(l, 32, 64);
    inv[tm] = 1.f / l;
  }
#pragma unroll
  for (int ct = 0; ct < 4; ++ct)
#pragma unroll
    for (int tm = 0; tm < 2; ++tm) {
      const int n = qt * 128 + w * 32 + tm * 16 + l16;
      const int h2 = ct * 2 + (quad >> 1);          // (ct*16+quad*4)>>3
      const int c2b = (quad & 1) * 4;
      float4 v4;
      v4.x = O[ct][tm][0] * inv[tm]; v4.y = O[ct][tm][1] * inv[tm];
      v4.z = O[ct][tm][2] * inv[tm]; v4.w = O[ct][tm][3] * inv[tm];
      *reinterpret_cast<float4*>(
          &out[(((long)(bi * 8 + h2)) * NSEQ + n) * 64 + h * 8 + c2b]) = v4;
    }
}

extern "C" void kernel_launch(void* const* d_in, const int* in_sizes, int n_in,
                              void* d_out, int out_size, void* d_ws, size_t ws_size,
                              hipStream_t stream) {
  (void)in_sizes; (void)n_in; (void)out_size; (void)ws_size;
  const float* x = (const float*)d_in[0];   // [8,8,2048,64] fp32
  const float* w = (const float*)d_in[1];   // [192,64] fp32
  float* out = (float*)d_out;               // [8,8,2048,64] fp32

  // workspace: Q(scaled),K natural + Vt transposed, bf16 bits, 16.78 MB each
  ushort_t* qws  = (ushort_t*)d_ws;
  ushort_t* kws  = qws + (size_t)BH * NSEQ * CDIM;
  ushort_t* vtws = kws + (size_t)BH * NSEQ * CDIM;

  qkv_proj_mfma<<<(BH * NSEQ) / 128, 256, 0, stream>>>(x, w, qws, kws, vtws);
  flash_attn_mfma<<<1024, 256, 0, stream>>>(qws, kws, vtws, out);
}

// Round 9
// 181.707 us; speedup vs baseline: 2.0955x; 1.1119x over previous
//
#include <hip/hip_runtime.h>
#include <math.h>

// Problem constants (B=8, H=8, N=2048, C=64). fp32 inputs/outputs.
// Q staged in d_ws as bf16 PRE-SCALED by C^-0.5 * log2(e) (flash uses exp2 =
// bare v_exp_f32). K natural [head][n][c]; V transposed Vt[head][c][n].
// Round 9: flash TQ=256/block (tm=4 per wave, grid 512 = 2 blocks/CU), TK=32,
// all LDS XOR-swizzled; proj uses swapped-operand mfma for Q/K (b64 d-packed
// stores) and normal orientation for V (b64 n-packed stores direct to Vt --
// no LDS transpose).
#define BH    64
#define NSEQ  2048
#define CDIM  64
#define WSTR  72   // proj Wb row stride in u16

typedef unsigned short ushort_t;
typedef __attribute__((ext_vector_type(8))) short short8;    // 8 bf16 (4 VGPR)
typedef __attribute__((ext_vector_type(4))) float float4v;   // mfma C/D

// fp32 -> bf16 bits, round-to-nearest-even
__device__ __forceinline__ ushort_t f32_to_bf16_rne(float x) {
  unsigned int u = __float_as_uint(x);
  u += 0x7fffu + ((u >> 16) & 1u);
  return (ushort_t)(u >> 16);
}

// pack 2 f32 -> 2 bf16 in a u32 (round-half-up)
__device__ __forceinline__ unsigned int pk2(float a, float b) {
  return ((__float_as_uint(a) + 0x8000u) >> 16) |
         ((__float_as_uint(b) + 0x8000u) & 0xffff0000u);
}

// async global->LDS, 16B per lane; LDS dest = wave-uniform base + lane*16
__device__ __forceinline__ void glds16(const ushort_t* g, ushort_t* l) {
  __builtin_amdgcn_global_load_lds(
      (const __attribute__((address_space(1))) void*)g,
      (__attribute__((address_space(3))) void*)l, 16, 0, 0);
}

// ---------------- QKV projection (MFMA, packed b64 stores) ----------------
// qkv[row, d] = sum_c x[row, c] * W[d, c];  d<64 -> Q (x 0.125*log2e), <128 -> K, else V.
// Q/K: acc = mfma(wf, xf)  -> lane holds 4 consecutive d for fixed row -> b64.
// V:   acc = mfma(xf, wf)  -> lane holds 4 consecutive rows (n) for fixed c
//      -> b64 straight into Vt[head][c][n] (transpose for free).
__global__ __launch_bounds__(256) void qkv_proj_mfma(
    const float* __restrict__ x, const float* __restrict__ w,
    ushort_t* __restrict__ q, ushort_t* __restrict__ k,
    ushort_t* __restrict__ vt) {
  __shared__ ushort_t Wb[192 * WSTR];   // 27648 B
  const int t = threadIdx.x;
  const int lane = t & 63, wv = t >> 6;
  const int quad = lane >> 4, l16 = lane & 15;
  const long rowbase = (long)blockIdx.x * 128;
  const int head  = (int)(rowbase >> 11);
  const int nbase = (int)(rowbase & 2047);

  // stage W as bf16; Q-rows (d<64) pre-scaled by 0.125*log2(e)
  for (int u = t; u < 1536; u += 256) {
    const int d = u >> 3, o8 = (u & 7) * 8;
    const float sc = (d < 64) ? 0.1803368801111244f : 1.0f;  // 0.125*log2(e)
    const float4 f0 = *reinterpret_cast<const float4*>(w + d * 64 + o8);
    const float4 f1 = *reinterpret_cast<const float4*>(w + d * 64 + o8 + 4);
    ushort_t tmp[8] __attribute__((aligned(16)));
    tmp[0] = f32_to_bf16_rne(f0.x * sc); tmp[1] = f32_to_bf16_rne(f0.y * sc);
    tmp[2] = f32_to_bf16_rne(f0.z * sc); tmp[3] = f32_to_bf16_rne(f0.w * sc);
    tmp[4] = f32_to_bf16_rne(f1.x * sc); tmp[5] = f32_to_bf16_rne(f1.y * sc);
    tmp[6] = f32_to_bf16_rne(f1.z * sc); tmp[7] = f32_to_bf16_rne(f1.w * sc);
    *reinterpret_cast<uint4*>(&Wb[d * WSTR + o8]) = *reinterpret_cast<const uint4*>(tmp);
  }
  __syncthreads();

  // A/B x-frags: x rows, converted to bf16
  short8 xf[2][2];
#pragma unroll
  for (int tm = 0; tm < 2; ++tm)
#pragma unroll
    for (int kb = 0; kb < 2; ++kb) {
      const float* xp = x + (rowbase + wv * 32 + tm * 16 + l16) * 64 + kb * 32 + quad * 8;
      const float4 f0 = *reinterpret_cast<const float4*>(xp);
      const float4 f1 = *reinterpret_cast<const float4*>(xp + 4);
      ushort_t tmp[8] __attribute__((aligned(16)));
      tmp[0] = f32_to_bf16_rne(f0.x); tmp[1] = f32_to_bf16_rne(f0.y);
      tmp[2] = f32_to_bf16_rne(f0.z); tmp[3] = f32_to_bf16_rne(f0.w);
      tmp[4] = f32_to_bf16_rne(f1.x); tmp[5] = f32_to_bf16_rne(f1.y);
      tmp[6] = f32_to_bf16_rne(f1.z); tmp[7] = f32_to_bf16_rne(f1.w);
      xf[tm][kb] = *reinterpret_cast<const short8*>(tmp);
    }

  float4v aqk[8][2];   // [d-tile][x-tile], swapped: D[d][row]
  float4v av[2][4];    // [x-tile][d-tile], normal: D[row][c]
#pragma unroll
  for (int nt = 0; nt < 8; ++nt)
#pragma unroll
    for (int tm = 0; tm < 2; ++tm)
#pragma unroll
      for (int r = 0; r < 4; ++r) aqk[nt][tm][r] = 0.f;
#pragma unroll
  for (int tm = 0; tm < 2; ++tm)
#pragma unroll
    for (int nt = 0; nt < 4; ++nt)
#pragma unroll
      for (int r = 0; r < 4; ++r) av[tm][nt][r] = 0.f;

#pragma unroll
  for (int kb = 0; kb < 2; ++kb) {
#pragma unroll
    for (int nt = 0; nt < 8; ++nt) {
      const short8 wf = *reinterpret_cast<const short8*>(
          &Wb[(nt * 16 + l16) * WSTR + kb * 32 + quad * 8]);
      aqk[nt][0] = __builtin_amdgcn_mfma_f32_16x16x32_bf16(wf, xf[0][kb], aqk[nt][0], 0, 0, 0);
      aqk[nt][1] = __builtin_amdgcn_mfma_f32_16x16x32_bf16(wf, xf[1][kb], aqk[nt][1], 0, 0, 0);
    }
#pragma unroll
    for (int nt = 0; nt < 4; ++nt) {
      const short8 wfv = *reinterpret_cast<const short8*>(
          &Wb[((128 + nt * 16) + l16) * WSTR + kb * 32 + quad * 8]);
      av[0][nt] = __builtin_amdgcn_mfma_f32_16x16x32_bf16(xf[0][kb], wfv, av[0][nt], 0, 0, 0);
      av[1][nt] = __builtin_amdgcn_mfma_f32_16x16x32_bf16(xf[1][kb], wfv, av[1][nt], 0, 0, 0);
    }
  }

  // Q/K stores: row = rowbase + wv*32+tm*16+l16, d = nt*16 + quad*4 + r
#pragma unroll
  for (int tm = 0; tm < 2; ++tm) {
    const long row = rowbase + wv * 32 + tm * 16 + l16;
#pragma unroll
    for (int nt = 0; nt < 8; ++nt) {
      uint2 pk;
      pk.x = pk2(aqk[nt][tm][0], aqk[nt][tm][1]);
      pk.y = pk2(aqk[nt][tm][2], aqk[nt][tm][3]);
      if (nt < 4)
        *reinterpret_cast<uint2*>(q + row * 64 + nt * 16 + quad * 4) = pk;
      else
        *reinterpret_cast<uint2*>(k + row * 64 + (nt - 4) * 16 + quad * 4) = pk;
    }
  }
  // V stores: c = nt*16 + l16, n = nbase + wv*32+tm*16+quad*4 + r
#pragma unroll
  for (int tm = 0; tm < 2; ++tm)
#pragma unroll
    for (int nt = 0; nt < 4; ++nt) {
      const int c = nt * 16 + l16;
      uint2 pk;
      pk.x = pk2(av[tm][nt][0], av[tm][nt][1]);
      pk.y = pk2(av[tm][nt][2], av[tm][nt][3]);
      *reinterpret_cast<uint2*>(vt + (long)head * (64 * 2048) + (long)c * 2048 +
                                nbase + wv * 32 + tm * 16 + quad * 4) = pk;
    }
}

// ---------------- MFMA flash attention (transposed dataflow, TQ=256) --------
// block: 256 threads = 4 waves, 64 q-rows per wave. TK=32. grid 512 (2/CU),
// XCD swizzle: bh = (id&7)*8 + (id>>3)&7, qt = id>>6.
// LDS (all XOR-swizzled, chunk = 8 u16 = 16B):
//   Ks2[2][32*64]: K tile [kv][c],  chunk' = chunk ^ (row&7)      (8 chunks/row)
//   Vs2[2][64*32]: Vt tile [c][kv], chunk' = chunk ^ ((row>>1)&3) (4 chunks/row)
//   Ps  [256*32]:  P [qrow][kv],    chunk' = chunk ^ ((row>>1)&3)
// mfma_f32_16x16x32_bf16: A/B lane map op[idx=lane&15][k=quad*8+j];
// C/D: reg r = D[row=quad*4+r][col=lane&15].
// S^T = mfma(kf, qf): reg r = S[qrow=tm*16+l16][kv=nt*16+quad*4+r] -> b64 pack.
// O^T = mfma(vf, pf): reg r = O[qrow=tm*16+l16][c=ct*16+quad*4+r] -> float4 out.
__global__ __launch_bounds__(256, 2) void flash_attn_mfma(
    const ushort_t* __restrict__ q, const ushort_t* __restrict__ k,
    const ushort_t* __restrict__ vt, float* __restrict__ out) {
  __shared__ ushort_t Ks2[2][32 * 64];  // 8 KB
  __shared__ ushort_t Vs2[2][64 * 32];  // 8 KB
  __shared__ ushort_t Ps[256 * 32];     // 16 KB, per-wave 64-row slices
  const int t = threadIdx.x;
  const int lane = t & 63, w = t >> 6;
  const int quad = lane >> 4, l16 = lane & 15;
  const int id = blockIdx.x;
  const int qt = id >> 6;
  const int bh = ((id & 7) << 3) | ((id >> 3) & 7);   // XCD-clustered heads
  const long hoff = (long)bh * NSEQ * CDIM;
  const ushort_t* qp  = q  + hoff + (long)qt * 256 * CDIM;
  const ushort_t* kp  = k  + hoff;
  const ushort_t* vtp = vt + hoff;     // [64][2048]

  // Q frags (pre-scaled), loaded once: B operand, Q[qrow=w*64+tm*16+l16][k]
  short8 qf[4][2];
#pragma unroll
  for (int tm = 0; tm < 4; ++tm)
#pragma unroll
    for (int kb = 0; kb < 2; ++kb)
      qf[tm][kb] = *reinterpret_cast<const short8*>(
          qp + (w * 64 + tm * 16 + l16) * 64 + kb * 32 + quad * 8);

  float4v O[4][4];   // [c-tile][q-tile]
  float rs[4];
#pragma unroll
  for (int tm = 0; tm < 4; ++tm) rs[tm] = 0.f;
#pragma unroll
  for (int ct = 0; ct < 4; ++ct)
#pragma unroll
    for (int tm = 0; tm < 4; ++tm)
#pragma unroll
      for (int r = 0; r < 4; ++r) O[ct][tm][r] = 0.f;

  // staging constants (per lane)
  const int krow = w * 8 + (lane >> 3);          // K: 8 rows/wave-call
  const int kchk = (lane & 7) ^ (lane >> 3);     // ^ (row & 7)
  const int kdst = w * 8 * 64;                   // u16
  const int vrow = w * 16 + (lane >> 2);         // V: 16 rows/wave-call
  const int vchk = (lane & 3) ^ ((lane >> 3) & 3);  // ^ ((row>>1) & 3)
  const int vdst = w * 16 * 32;                  // u16
  const int pswz = (l16 >> 1) & 3;               // Ps/Vs read swizzle term

  // prologue: stage tile 0 into buffer 0
  glds16(kp + (long)krow * 64 + kchk * 8, &Ks2[0][kdst]);
  glds16(vtp + (long)vrow * 2048 + vchk * 8, &Vs2[0][vdst]);

  for (int tile = 0; tile < NSEQ / 32; ++tile) {
    const int cur = tile & 1;
    __syncthreads();   // implicit vmcnt(0): buf[cur] ready; buf[1-cur] free
    if (tile < NSEQ / 32 - 1) {
      const long nxt = tile + 1;
      glds16(kp + (nxt * 32 + krow) * 64 + kchk * 8, &Ks2[1 - cur][kdst]);
      glds16(vtp + (long)vrow * 2048 + nxt * 32 + vchk * 8, &Vs2[1 - cur][vdst]);
    }

    // S^T = K Q^T  (2 kv-tiles x 4 q-tiles of 16x16 per wave)
    float4v s[2][4];
#pragma unroll
    for (int nt = 0; nt < 2; ++nt)
#pragma unroll
      for (int tm = 0; tm < 4; ++tm)
#pragma unroll
        for (int r = 0; r < 4; ++r) s[nt][tm][r] = 0.f;

#pragma unroll
    for (int kb = 0; kb < 2; ++kb) {
      short8 kf[2];   // A: K[kv=nt*16+l16][k=kb*32+quad*8+j]
#pragma unroll
      for (int nt = 0; nt < 2; ++nt)
        kf[nt] = *reinterpret_cast<const short8*>(
            &Ks2[cur][(nt * 16 + l16) * 64 + (((kb * 4 + quad) ^ (l16 & 7)) * 8)]);
#pragma unroll
      for (int nt = 0; nt < 2; ++nt)
#pragma unroll
        for (int tm = 0; tm < 4; ++tm)
          s[nt][tm] = __builtin_amdgcn_mfma_f32_16x16x32_bf16(
              kf[nt], qf[tm][kb], s[nt][tm], 0, 0, 0);
    }

    // p = exp2(s'); lane-private partial sums; b64 pack into Ps[qrow][kv]
#pragma unroll
    for (int tm = 0; tm < 4; ++tm)
#pragma unroll
      for (int nt = 0; nt < 2; ++nt) {
        const float p0 = __builtin_amdgcn_exp2f(s[nt][tm][0]);
        const float p1 = __builtin_amdgcn_exp2f(s[nt][tm][1]);
        const float p2 = __builtin_amdgcn_exp2f(s[nt][tm][2]);
        const float p3 = __builtin_amdgcn_exp2f(s[nt][tm][3]);
        rs[tm] += (p0 + p1) + (p2 + p3);
        uint2 pk;
        pk.x = pk2(p0, p1);
        pk.y = pk2(p2, p3);
        *reinterpret_cast<uint2*>(
            &Ps[(w * 64 + tm * 16 + l16) * 32 +
                (((nt * 2 + (quad >> 1)) ^ pswz) * 8) + (quad & 1) * 4]) = pk;
      }

    // O^T += Vt P^T  (wave-private Ps slice -> no barrier; k-depth = 32)
    {
      short8 pf[4], vf[4];
#pragma unroll
      for (int tm = 0; tm < 4; ++tm)
        pf[tm] = *reinterpret_cast<const short8*>(
            &Ps[(w * 64 + tm * 16 + l16) * 32 + ((quad ^ pswz) * 8)]);
#pragma unroll
      for (int ct = 0; ct < 4; ++ct)
        vf[ct] = *reinterpret_cast<const short8*>(
            &Vs2[cur][(ct * 16 + l16) * 32 + ((quad ^ pswz) * 8)]);
#pragma unroll
      for (int ct = 0; ct < 4; ++ct)
#pragma unroll
        for (int tm = 0; tm < 4; ++tm)
          O[ct][tm] = __builtin_amdgcn_mfma_f32_16x16x32_bf16(
              vf[ct], pf[tm], O[ct][tm], 0, 0, 0);
    }
  }

  // epilogue: quad-reduce row sums, normalize, head-mix shuffle, float4 out
  // final[b, h2, n, h*8+c2] = out_head[b, h, n, h2*8+c2]
  const int bi = bh >> 3, h = bh & 7;
  float inv[4];
#pragma unroll
  for (int tm = 0; tm < 4; ++tm) {
    float l = rs[tm];
    l += __shfl_xor(l, 16, 64);
    l += __shfl_xor(l, 32, 64);
    inv[tm] = 1.f / l;
  }
#pragma unroll
  for (int ct = 0; ct < 4; ++ct)
#pragma unroll
    for (int tm = 0; tm < 4; ++tm) {
      const int n = qt * 256 + w * 64 + tm * 16 + l16;
      const int h2 = ct * 2 + (quad >> 1);          // (ct*16+quad*4)>>3
      const int c2b = (quad & 1) * 4;
      float4 v4;
      v4.x = O[ct][tm][0] * inv[tm]; v4.y = O[ct][tm][1] * inv[tm];
      v4.z = O[ct][tm][2] * inv[tm]; v4.w = O[ct][tm][3] * inv[tm];
      *reinterpret_cast<float4*>(
          &out[(((long)(bi * 8 + h2)) * NSEQ + n) * 64 + h * 8 + c2b]) = v4;
    }
}

extern "C" void kernel_launch(void* const* d_in, const int* in_sizes, int n_in,
                              void* d_out, int out_size, void* d_ws, size_t ws_size,
                              hipStream_t stream) {
  (void)in_sizes; (void)n_in; (void)out_size; (void)ws_size;
  const float* x = (const float*)d_in[0];   // [8,8,2048,64] fp32
  const float* w = (const float*)d_in[1];   // [192,64] fp32
  float* out = (float*)d_out;               // [8,8,2048,64] fp32

  // workspace: Q(scaled),K natural + Vt transposed, bf16 bits, 16.78 MB each
  ushort_t* qws  = (ushort_t*)d_ws;
  ushort_t* kws  = qws + (size_t)BH * NSEQ * CDIM;
  ushort_t* vtws = kws + (size_t)BH * NSEQ * CDIM;

  qkv_proj_mfma<<<(BH * NSEQ) / 128, 256, 0, stream>>>(x, w, qws, kws, vtws);
  flash_attn_mfma<<<512, 256, 0, stream>>>(qws, kws, vtws, out);
}